// Round 1
// 1027.934 us; speedup vs baseline: 1.0148x; 1.0148x over previous
//
#include <hip/hip_runtime.h>

typedef int v4i __attribute__((ext_vector_type(4)));

#define GLOBAL_AS(p) ((const __attribute__((address_space(1))) void*)(p))
#define LDS_AS(p)    ((__attribute__((address_space(3))) void*)(p))

// ---------------------------------------------------------------------------
// Kernel 1: static quantize x fp32 -> int8  (x/s, clip, round-half-even)
// (unchanged — verified bit-exact path)
// ---------------------------------------------------------------------------
__global__ __launch_bounds__(256) void quant_kernel(
    const float* __restrict__ x, signed char* __restrict__ xq,
    const float* __restrict__ iscale, int n4)
{
    int idx = blockIdx.x * 256 + threadIdx.x;
    if (idx >= n4) return;
    float s = iscale[0];
    float4 v = ((const float4*)x)[idx];
    int b0 = (int)rintf(fminf(fmaxf(v.x / s, -128.f), 127.f));
    int b1 = (int)rintf(fminf(fmaxf(v.y / s, -128.f), 127.f));
    int b2 = (int)rintf(fminf(fmaxf(v.z / s, -128.f), 127.f));
    int b3 = (int)rintf(fminf(fmaxf(v.w / s, -128.f), 127.f));
    unsigned packed = (unsigned)(b0 & 255) | ((unsigned)(b1 & 255) << 8) |
                      ((unsigned)(b2 & 255) << 16) | ((unsigned)(b3 & 255) << 24);
    ((unsigned*)xq)[idx] = packed;
}

// ---------------------------------------------------------------------------
// Kernel 2: transpose qweight [K,N] (int32 storage) -> [N,K] int8 (unchanged)
// ---------------------------------------------------------------------------
__global__ __launch_bounds__(256) void transpose_kernel(
    const int* __restrict__ in, signed char* __restrict__ out,
    int K, int N)
{
    __shared__ unsigned char t[64][68];
    const int n0 = blockIdx.x * 64;
    const int k0 = blockIdx.y * 64;
    const int tid = threadIdx.x;

#pragma unroll
    for (int i = 0; i < 4; i++) {
        int d = tid + i * 256;
        int r = d >> 4, c = d & 15;
        int4 v = *(const int4*)(in + (size_t)(k0 + r) * N + n0 + c * 4);
        unsigned o = (unsigned)(v.x & 255) | ((unsigned)(v.y & 255) << 8) |
                     ((unsigned)(v.z & 255) << 16) | ((unsigned)(v.w & 255) << 24);
        *(unsigned*)&t[r][c * 4] = o;
    }
    __syncthreads();
#pragma unroll
    for (int i = 0; i < 4; i++) {
        int d = tid + i * 256;
        int n = d >> 4, b = d & 15;
        unsigned o = (unsigned)t[4 * b + 0][n]
                   | ((unsigned)t[4 * b + 1][n] << 8)
                   | ((unsigned)t[4 * b + 2][n] << 16)
                   | ((unsigned)t[4 * b + 3][n] << 24);
        *(unsigned*)(out + (size_t)(n0 + n) * K + k0 + b * 4) = o;
    }
}

// ---------------------------------------------------------------------------
// Kernel 3: int8 GEMM — 256x256 tile, 8-phase schedule (T1+T2+T3+T4+T5 port).
//   A  = x_int8  [M,K] row-major; Bt = qweight^T [N,K] row-major.
//   8 waves (512 thr): wave (wm,wn) = ((w>>2)*128, (w&3)*64); per-wave 128x64
//   output as acc[8][4] frags of mfma_i32_16x16x64_i8.
//   LDS: 4-slot ring per operand, slot = 256 rows x 64 B (16 KiB). 128 KiB tot.
//   Pipeline: while computing K-tile t (2 phases), stage tile t+3 into slot
//   (t+3)&3 = (t-1)&3 (whose tile t-1 was fully read before the barrier that
//   precedes this phase). One counted vmcnt(8) per tile (12 loads in flight;
//   oldest 4 = tile t+1) — never vmcnt(0) in the main loop.
//   T2 swizzle: global_load_lds dest is linear; global SOURCE col is
//   pre-swizzled ((t&3)^((t>>3)&3))*16; ds_read uses slot quad^((r15>>1)&3).
//   (involution, both-sides — 2 lanes/16B window = conflict-free floor)
// ---------------------------------------------------------------------------
#define BM 256
#define BN 256
#define BK 64

#define STAGE_A(ss, kk) do { \
    __builtin_amdgcn_global_load_lds(GLOBAL_AS(pA0 + (kk)), LDS_AS(&lA[ss][stg0]), 16, 0, 0); \
    __builtin_amdgcn_global_load_lds(GLOBAL_AS(pA1 + (kk)), LDS_AS(&lA[ss][stg1]), 16, 0, 0); \
} while (0)

#define STAGE_B(ss, kk) do { \
    __builtin_amdgcn_global_load_lds(GLOBAL_AS(pB0 + (kk)), LDS_AS(&lB[ss][stg0]), 16, 0, 0); \
    __builtin_amdgcn_global_load_lds(GLOBAL_AS(pB1 + (kk)), LDS_AS(&lB[ss][stg1]), 16, 0, 0); \
} while (0)

#define TILE(j) do { \
    const int ss = (j); const int sp = ((j) + 3) & 3; \
    int kpre = (t0 + (j) + 3) << 6; \
    if (kpre >= K) kpre -= K;   /* wrapped dummy stage keeps vmcnt counts uniform */ \
    const signed char* pa = &lA[ss][aoffL]; \
    const signed char* pb = &lB[ss][boffL]; \
    v4i aF0[4], aF1[4], bF[4]; \
    /* ---- even phase: A rows 0-63 (per-wave half) x all B, ksub full ---- */ \
    _Pragma("unroll") for (int i = 0; i < 4; ++i) aF0[i] = *(const v4i*)(pa + i * 1024); \
    _Pragma("unroll") for (int i = 0; i < 4; ++i) bF[i]  = *(const v4i*)(pb + i * 1024); \
    STAGE_A(sp, kpre); \
    __builtin_amdgcn_s_barrier(); \
    asm volatile("s_waitcnt lgkmcnt(0)" ::: "memory"); \
    __builtin_amdgcn_sched_barrier(0); \
    __builtin_amdgcn_s_setprio(1); \
    _Pragma("unroll") for (int mi = 0; mi < 4; ++mi) \
        _Pragma("unroll") for (int ni = 0; ni < 4; ++ni) \
            acc[mi][ni] = __builtin_amdgcn_mfma_i32_16x16x64_i8(aF0[mi], bF[ni], acc[mi][ni], 0, 0, 0); \
    __builtin_amdgcn_s_setprio(0); \
    __builtin_amdgcn_s_barrier(); \
    /* ---- odd phase: A rows 64-127, B regs reused ---- */ \
    _Pragma("unroll") for (int i = 0; i < 4; ++i) aF1[i] = *(const v4i*)(pa + (4 + i) * 1024); \
    STAGE_B(sp, kpre); \
    __builtin_amdgcn_s_barrier(); \
    asm volatile("s_waitcnt lgkmcnt(0)" ::: "memory"); \
    __builtin_amdgcn_sched_barrier(0); \
    __builtin_amdgcn_s_setprio(1); \
    _Pragma("unroll") for (int mi = 0; mi < 4; ++mi) \
        _Pragma("unroll") for (int ni = 0; ni < 4; ++ni) \
            acc[4 + mi][ni] = __builtin_amdgcn_mfma_i32_16x16x64_i8(aF1[mi], bF[ni], acc[4 + mi][ni], 0, 0, 0); \
    __builtin_amdgcn_s_setprio(0); \
    asm volatile("s_waitcnt vmcnt(8)" ::: "memory");  /* tile t+1 landed; t+2,t+3 in flight */ \
    __builtin_amdgcn_s_barrier(); \
} while (0)

__global__ __launch_bounds__(512, 2) void gemm_i8_kernel(
    const signed char* __restrict__ A,
    const signed char* __restrict__ Bt,
    float* __restrict__ out,
    const float* __restrict__ wscale,
    const float* __restrict__ iscale,
    int M, int N, int K)
{
    __shared__ __align__(16) signed char lA[4][BM * BK];   // 4 x 16 KiB
    __shared__ __align__(16) signed char lB[4][BN * BK];   // 4 x 16 KiB

    const int tid  = threadIdx.x;
    const int wave = tid >> 6;
    const int lane = tid & 63;

    // ---- T1: bijective XCD swizzle (m204 form), bn-major within chunks ----
    const int nwg = gridDim.x;
    const int q = nwg >> 3, r = nwg & 7;
    const int xcd = blockIdx.x & 7, o = blockIdx.x >> 3;
    const int swz = (xcd < r ? xcd * (q + 1) : r * (q + 1) + (xcd - r) * q) + o;
    const int nbm = M >> 8;
    const int bm = swz % nbm;
    const int bn = swz / nbm;

    // ---- staging source (pre-swizzled col so linear LDS dest reads swizzled)
    const int srow = tid >> 2;                                  // 0..127
    const int scol = ((tid & 3) ^ ((tid >> 3) & 3)) << 4;       // slot^swz(row)
    const signed char* pA0 = A  + (size_t)((bm << 8) + srow) * K + scol;
    const signed char* pA1 = pA0 + (size_t)128 * K;
    const signed char* pB0 = Bt + (size_t)((bn << 8) + srow) * K + scol;
    const signed char* pB1 = pB0 + (size_t)128 * K;
    const int stg0 = wave << 10;            // wave-uniform LDS bases (+lane*16 by HW)
    const int stg1 = 8192 + (wave << 10);

    // ---- compute-side lane constants ----
    const int r15  = lane & 15;
    const int quad = lane >> 4;
    const int wm = (wave >> 2) << 7;        // 0 / 128
    const int wn = (wave & 3) << 6;         // 0 / 64 / 128 / 192
    const int swzs = (r15 >> 1) & 3;
    const int aoffL = (wm + r15) * 64 + ((quad ^ swzs) << 4);
    const int boffL = (wn + r15) * 64 + ((quad ^ swzs) << 4);

    v4i acc[8][4] = {};

    // ---- prologue: stage tiles 0,1,2 (12 loads), land tile 0 -------------
    STAGE_A(0, 0);   STAGE_B(0, 0);
    STAGE_A(1, 64);  STAGE_B(1, 64);
    STAGE_A(2, 128); STAGE_B(2, 128);
    asm volatile("s_waitcnt vmcnt(8)" ::: "memory");  // oldest 4 = tile 0
    __builtin_amdgcn_s_barrier();

    const int NT = K >> 6;                   // 64 tiles; NT % 4 == 0
#pragma unroll 1
    for (int t0 = 0; t0 < NT; t0 += 4) {
        TILE(0);
        TILE(1);
        TILE(2);
        TILE(3);
    }

    // ---- epilogue: dequant + store (C/D: col=lane&15, row=quad*4+reg) ----
    const float isc = iscale[0];
    const int orow = (bm << 8) + wm + (quad << 2);
#pragma unroll
    for (int ni = 0; ni < 4; ++ni) {
        const int ncol = (bn << 8) + wn + ni * 16 + r15;
        const float sc = isc * wscale[ncol];
        float* obase = out + (size_t)orow * N + ncol;
#pragma unroll
        for (int mi = 0; mi < 8; ++mi) {
#pragma unroll
            for (int rr = 0; rr < 4; ++rr) {
                obase[(size_t)(mi * 16 + rr) * N] = (float)acc[mi][ni][rr] * sc;
            }
        }
    }
}

// ---------------------------------------------------------------------------
extern "C" void kernel_launch(void* const* d_in, const int* in_sizes, int n_in,
                              void* d_out, int out_size, void* d_ws, size_t ws_size,
                              hipStream_t stream) {
    const float* x      = (const float*)d_in[0];
    const int*   qw     = (const int*)d_in[1];      // int8 values, int32 storage
    const float* wscale = (const float*)d_in[2];
    const float* iscale = (const float*)d_in[3];
    float*       out    = (float*)d_out;

    const int N = in_sizes[2];            // 11008
    const int K = in_sizes[1] / N;        // 4096
    const int M = in_sizes[0] / K;        // 8192

    signed char* xq  = (signed char*)d_ws;                     // [M,K]
    signed char* qwT = (signed char*)d_ws + (size_t)M * K;     // [N,K]

    // 1) quantize activations
    {
        int n4 = (M * K) / 4;
        quant_kernel<<<(n4 + 255) / 256, 256, 0, stream>>>(x, xq, iscale, n4);
    }
    // 2) transpose weights to K-contiguous int8
    {
        dim3 grid(N / 64, K / 64);
        transpose_kernel<<<grid, 256, 0, stream>>>(qw, qwT, K, N);
    }
    // 3) int8 GEMM + fused dequant — 256^2 tiles, 8-phase pipeline
    {
        int nwg = (M >> 8) * (N >> 8);    // 32 * 43 = 1376 (div by 8)
        gemm_i8_kernel<<<nwg, 512, 0, stream>>>(xq, qwT, out, wscale, iscale, M, N, K);
    }
}